// Round 1
// baseline (608.533 us; speedup 1.0000x reference)
//
#include <hip/hip_runtime.h>
#include <stdint.h>

// AnyprecisionLinear: out[s,o] = sum_k x[s,k] * lut[o, (code(o,k))>>4]
// M=2048 (s), N=8192 (o), K=8192. fp32 in/out, bf16 MFMA compute
// (threshold 12.48 allows bf16: 8x bf16-eps scaled).
//
// Strategy (m97 recipe from the verified ladder):
//   K1: dequant qweight -> bf16 W (N x K) in workspace   (~35 us, mem-bound)
//   K2: cast x fp32 -> bf16 (M x K) in workspace          (~18 us, mem-bound)
//   K3: gemm_bt 128x128x64 tile, mfma_f32_16x16x32_bf16,
//       global_load_lds width=16 staging, 4 waves x 4x4 acc tiles.

#define M_DIM 2048
#define N_DIM 8192
#define K_DIM 8192
#define BM 128
#define BN 128
#define BK 64

typedef __bf16 bf16x8 __attribute__((ext_vector_type(8)));
typedef float f32x4 __attribute__((ext_vector_type(4)));

__device__ __forceinline__ unsigned short f2bf(float f) {
  // round-to-nearest-even fp32 -> bf16 (no NaN handling needed: inputs finite)
  unsigned int u = __float_as_uint(f);
  unsigned int r = (u + 0x7FFFu + ((u >> 16) & 1u)) >> 16;
  return (unsigned short)r;
}

__device__ __forceinline__ ushort4 deq_word(unsigned int q, const float* __restrict__ l) {
  ushort4 r;
  r.x = f2bf(l[(q >> 4) & 15u]);   // code j=0: (q & 0xFF) >> 4
  r.y = f2bf(l[(q >> 12) & 15u]);  // j=1
  r.z = f2bf(l[(q >> 20) & 15u]);  // j=2
  r.w = f2bf(l[(q >> 28) & 15u]);  // j=3
  return r;
}

// One thread per int4 (4 packed words -> 16 bf16 weights = 32 B out).
// K/4 = 2048 words per output row; idx*4 .. idx*4+3 always within one row.
__global__ void dequant_kernel(const int4* __restrict__ qw4,
                               const float* __restrict__ lut,
                               unsigned short* __restrict__ wb) {
  int idx = blockIdx.x * 256 + threadIdx.x;          // int4 index
  int4 q4 = qw4[idx];
  int word0 = idx << 2;
  const float* l = lut + ((word0 >> 11) << 4);       // row = word0 / 2048
  ushort4* dst = (ushort4*)(wb + (size_t)idx * 16);
  dst[0] = deq_word((unsigned int)q4.x, l);
  dst[1] = deq_word((unsigned int)q4.y, l);
  dst[2] = deq_word((unsigned int)q4.z, l);
  dst[3] = deq_word((unsigned int)q4.w, l);
}

__global__ void cvt_x_kernel(const float4* __restrict__ x4,
                             unsigned short* __restrict__ xb) {
  int idx = blockIdx.x * 256 + threadIdx.x;          // float4 index
  float4 v = x4[idx];
  ushort4 r;
  r.x = f2bf(v.x); r.y = f2bf(v.y); r.z = f2bf(v.z); r.w = f2bf(v.w);
  *(ushort4*)(xb + (size_t)idx * 4) = r;
}

// C = A * B^T, A: M x K bf16 row-major, B: N x K bf16 row-major, C: M x N fp32.
// Block 256 thr (4 waves), tile 128x128, BK=64, 32 KB LDS single-buffered.
// Wave grid 2x2, each wave 4x4 tiles of 16x16.
__global__ __launch_bounds__(256) void gemm_bt(
    const unsigned short* __restrict__ A,
    const unsigned short* __restrict__ B,
    float* __restrict__ C) {
  __shared__ __align__(16) unsigned short sA[BM * BK];  // 16 KB
  __shared__ __align__(16) unsigned short sB[BN * BK];  // 16 KB

  const int tid = threadIdx.x;
  const int wave = tid >> 6;
  const int lane = tid & 63;
  const int m0 = blockIdx.y * BM;
  const int n0 = blockIdx.x * BN;
  const int wm = (wave & 1) * 64;   // wave's M offset in tile
  const int wn = (wave >> 1) * 64;  // wave's N offset in tile

  // staging: 16 chunks of 1024 B per tile; wave w owns chunks w*4..w*4+3.
  // Within a chunk: lane i -> row chunk*8 + i/8, col (i%8)*8 (8 bf16 = 16 B).
  // LDS dest is wave-uniform base; HW scatters lane*16 B -> flat = chunk*1024 + 16*i,
  // which equals row-major (row*64+col)*2 exactly (no padding allowed!).
  const int srow = lane >> 3;
  const int scol = (lane & 7) * 8;

  const int laneM = lane & 15;         // A/B operand row (m or n)
  const int laneK = (lane >> 4) * 8;   // k quad offset

  f32x4 acc[4][4];
#pragma unroll
  for (int i = 0; i < 4; ++i)
#pragma unroll
    for (int j = 0; j < 4; ++j)
      acc[i][j] = (f32x4){0.0f, 0.0f, 0.0f, 0.0f};

  for (int k0 = 0; k0 < K_DIM; k0 += BK) {
#pragma unroll
    for (int r = 0; r < 4; ++r) {
      const int chunk = wave * 4 + r;
      const int row = chunk * 8 + srow;
      const unsigned short* ga = A + (size_t)(m0 + row) * K_DIM + k0 + scol;
      __builtin_amdgcn_global_load_lds(
          (const __attribute__((address_space(1))) void*)ga,
          (__attribute__((address_space(3))) void*)(sA + chunk * 512),
          16, 0, 0);
      const unsigned short* gb = B + (size_t)(n0 + row) * K_DIM + k0 + scol;
      __builtin_amdgcn_global_load_lds(
          (const __attribute__((address_space(1))) void*)gb,
          (__attribute__((address_space(3))) void*)(sB + chunk * 512),
          16, 0, 0);
    }
    __syncthreads();  // compiler emits vmcnt(0) drain before barrier

#pragma unroll
    for (int kk = 0; kk < BK; kk += 32) {
      bf16x8 af[4], bfr[4];
#pragma unroll
      for (int t = 0; t < 4; ++t) {
        af[t]  = *(const bf16x8*)(sA + (wm + t * 16 + laneM) * BK + kk + laneK);
        bfr[t] = *(const bf16x8*)(sB + (wn + t * 16 + laneM) * BK + kk + laneK);
      }
#pragma unroll
      for (int i = 0; i < 4; ++i)
#pragma unroll
        for (int j = 0; j < 4; ++j)
          acc[i][j] = __builtin_amdgcn_mfma_f32_16x16x32_bf16(
              af[i], bfr[j], acc[i][j], 0, 0, 0);
    }
    __syncthreads();
  }

  // C/D layout: col = lane&15, row = (lane>>4)*4 + reg  [m89/m91]
  const int crow = wm + ((lane >> 4) << 2);
  const int ccol = wn + (lane & 15);
#pragma unroll
  for (int i = 0; i < 4; ++i)
#pragma unroll
    for (int j = 0; j < 4; ++j) {
      float* cp = C + (size_t)(m0 + crow + i * 16) * N_DIM + (n0 + ccol + j * 16);
#pragma unroll
      for (int r2 = 0; r2 < 4; ++r2)
        cp[(size_t)r2 * N_DIM] = acc[i][j][r2];
    }
}

// Safety-net fallback (only if ws_size < 160 MB): correct fp32, slow.
__global__ void naive_kernel(const float* __restrict__ x,
                             const int* __restrict__ qw,
                             const float* __restrict__ lut,
                             float* __restrict__ out) {
  int o = blockIdx.x * blockDim.x + threadIdx.x;
  int s = blockIdx.y;
  const float* xr = x + (size_t)s * K_DIM;
  const unsigned int* qr = (const unsigned int*)qw + (size_t)o * (K_DIM / 4);
  const float* l = lut + o * 16;
  float acc = 0.f;
  for (int w = 0; w < K_DIM / 4; ++w) {
    unsigned int q = qr[w];
    acc += xr[w * 4 + 0] * l[(q >> 4) & 15u]
         + xr[w * 4 + 1] * l[(q >> 12) & 15u]
         + xr[w * 4 + 2] * l[(q >> 20) & 15u]
         + xr[w * 4 + 3] * l[(q >> 28) & 15u];
  }
  out[(size_t)s * N_DIM + o] = acc;
}

extern "C" void kernel_launch(void* const* d_in, const int* in_sizes, int n_in,
                              void* d_out, int out_size, void* d_ws, size_t ws_size,
                              hipStream_t stream) {
  const float* x   = (const float*)d_in[0];
  const int*   qw  = (const int*)d_in[1];
  const float* lut = (const float*)d_in[2];
  float* out = (float*)d_out;

  const size_t wb_elems = (size_t)N_DIM * K_DIM;   // 128 MB bf16
  const size_t xb_elems = (size_t)M_DIM * K_DIM;   //  32 MB bf16
  const size_t need = (wb_elems + xb_elems) * sizeof(unsigned short);

  if (ws_size >= need) {
    unsigned short* wb = (unsigned short*)d_ws;
    unsigned short* xb = wb + wb_elems;

    const int n_int4 = N_DIM * (K_DIM / 4) / 4;    // 4,194,304
    hipLaunchKernelGGL(dequant_kernel, dim3(n_int4 / 256), dim3(256), 0, stream,
                       (const int4*)qw, lut, wb);

    const int n_f4 = M_DIM * K_DIM / 4;            // 4,194,304
    hipLaunchKernelGGL(cvt_x_kernel, dim3(n_f4 / 256), dim3(256), 0, stream,
                       (const float4*)x, xb);

    dim3 grid(N_DIM / BN, M_DIM / BM);             // 64 x 16 = 1024 blocks
    hipLaunchKernelGGL(gemm_bt, grid, dim3(256), 0, stream, xb, wb, out);
  } else {
    dim3 grid(N_DIM / 256, M_DIM);
    hipLaunchKernelGGL(naive_kernel, grid, dim3(256), 0, stream, x, qw, lut, out);
  }
}

// Round 2
// 532.502 us; speedup vs baseline: 1.1428x; 1.1428x over previous
//
#include <hip/hip_runtime.h>
#include <stdint.h>

// AnyprecisionLinear: out[s,o] = sum_k x[s,k] * lut[o, code(o,k)>>4]
// M=2048, N=8192, K=8192. fp32 in/out, bf16 MFMA compute.
//
// R2 changes vs R1:
//  - gemm_bt: XOR-swizzled LDS layout (global chunk c^(row&7) stored at LDS
//    chunk c) to kill the 1.0e8 SQ_LDS_BANK_CONFLICT cycles (row stride was
//    128 B = 32 banks -> 16-way conflicts on fragment reads).
//  - dequant: one block per output row, bf16 LUT in LDS with 64 lane-private
//    copies at 68 B stride (17 coprime 32 -> conflict-free ds_read_u16
//    gathers), int4 reads + 16 B stores.
//  - cvt_x: 8 elements/thread, 16 B stores.

#define M_DIM 2048
#define N_DIM 8192
#define K_DIM 8192
#define BM 128
#define BN 128
#define BK 64

typedef __bf16 bf16x8 __attribute__((ext_vector_type(8)));
typedef float f32x4 __attribute__((ext_vector_type(4)));

__device__ __forceinline__ unsigned int f2bf(float f) {
  // round-to-nearest-even fp32 -> bf16
  unsigned int u = __float_as_uint(f);
  return (u + 0x7FFFu + ((u >> 16) & 1u)) >> 16;
}

// ---------------- dequant: qweight (int32-packed 8-bit codes) -> bf16 W ----
// One block per output row (8192 blocks, 256 threads).
// LDS LUT: 64 copies (one per lane id) at stride 34 ushorts (68 B) so lane l
// gathering entry e hits bank (17*l + e/2) % 32 -> 17 coprime 32 => lanes
// 0..31 all on distinct banks, lanes 32..63 are the free 2-way alias.
__global__ __launch_bounds__(256) void dequant_kernel(
    const int4* __restrict__ qw4,
    const float* __restrict__ lut,
    unsigned short* __restrict__ wb) {
  __shared__ unsigned short slut[64 * 34];  // 4352 B
  const int row = blockIdx.x;
  const int tid = threadIdx.x;

  for (int t = tid; t < 64 * 16; t += 256) {
    int c = t >> 4, e = t & 15;
    slut[c * 34 + e] = (unsigned short)f2bf(lut[row * 16 + e]);
  }
  __syncthreads();

  const unsigned short* myl = slut + (tid & 63) * 34;
  const int4* src = qw4 + (size_t)row * 512;                 // 512 int4 per row
  unsigned short* dst = wb + (size_t)row * (size_t)K_DIM;

#pragma unroll
  for (int h = 0; h < 2; ++h) {
    const int i4 = h * 256 + tid;
    int4 q = src[i4];
    unsigned int w[4] = {(unsigned int)q.x, (unsigned int)q.y,
                         (unsigned int)q.z, (unsigned int)q.w};
    unsigned int v[16];
#pragma unroll
    for (int j = 0; j < 4; ++j) {
#pragma unroll
      for (int k = 0; k < 4; ++k) {
        v[j * 4 + k] = myl[(w[j] >> (8 * k + 4)) & 15u];
      }
    }
    uint4 o0, o1;
    o0.x = v[0] | (v[1] << 16);  o0.y = v[2]  | (v[3] << 16);
    o0.z = v[4] | (v[5] << 16);  o0.w = v[6]  | (v[7] << 16);
    o1.x = v[8] | (v[9] << 16);  o1.y = v[10] | (v[11] << 16);
    o1.z = v[12] | (v[13] << 16); o1.w = v[14] | (v[15] << 16);
    uint4* dp = (uint4*)(dst + (size_t)i4 * 16);
    dp[0] = o0;
    dp[1] = o1;
  }
}

// ---------------- x fp32 -> bf16, 8 elements/thread, 16 B stores -----------
__global__ __launch_bounds__(256) void cvt_x_kernel(
    const float4* __restrict__ x4, unsigned int* __restrict__ xb) {
  const int idx = blockIdx.x * 256 + threadIdx.x;
  float4 a = x4[2 * idx];
  float4 b = x4[2 * idx + 1];
  uint4 o;
  o.x = f2bf(a.x) | (f2bf(a.y) << 16);
  o.y = f2bf(a.z) | (f2bf(a.w) << 16);
  o.z = f2bf(b.x) | (f2bf(b.y) << 16);
  o.w = f2bf(b.z) | (f2bf(b.w) << 16);
  ((uint4*)xb)[idx] = o;
}

// ---------------- GEMM: C = A * B^T, bf16 MFMA, XOR-swizzled LDS -----------
// A: M x K bf16 row-major, B: N x K bf16 row-major, C: M x N fp32.
// Block 256 thr (4 waves), tile 128x128, BK=64, 32 KB LDS single-buffered.
//
// LDS layout: [row][8 chunks of 8 bf16]; LDS chunk c of row r holds GLOBAL
// k-chunk (c ^ (r & 7)). Staging achieves this by swizzling the global source
// column per lane: lane i of a chunk-load covers LDS flat (row=chunk*8+i/8,
// c=i&7) and therefore loads global chunk (i&7)^(i>>3) (i>>3 == row&7).
// Fragment read: global chunk g = kk/8 + q lives at LDS chunk g ^ (laneM&7)
// -> lanes 0..7 hit banks 4*(g^m): full 32-bank spread, conflict-free.
__global__ __launch_bounds__(256) void gemm_bt(
    const unsigned short* __restrict__ A,
    const unsigned short* __restrict__ B,
    float* __restrict__ C) {
  __shared__ __align__(16) unsigned short sA[BM * BK];  // 16 KB
  __shared__ __align__(16) unsigned short sB[BN * BK];  // 16 KB

  const int tid = threadIdx.x;
  const int wave = tid >> 6;
  const int lane = tid & 63;
  const int m0 = blockIdx.y * BM;
  const int n0 = blockIdx.x * BN;
  const int wm = (wave & 1) * 64;
  const int wn = (wave >> 1) * 64;

  // staging source coords for this lane (swizzled column)
  const int srow = lane >> 3;                       // row within chunk (0..7)
  const int scol = ((lane & 7) ^ (lane >> 3)) * 8;  // swizzled global k-chunk

  const int laneM = lane & 15;   // operand m/n index
  const int q = lane >> 4;       // k-quad
  const int sw = laneM & 7;      // reader XOR key (== row&7)

  f32x4 acc[4][4];
#pragma unroll
  for (int i = 0; i < 4; ++i)
#pragma unroll
    for (int j = 0; j < 4; ++j)
      acc[i][j] = (f32x4){0.0f, 0.0f, 0.0f, 0.0f};

  for (int k0 = 0; k0 < K_DIM; k0 += BK) {
#pragma unroll
    for (int r = 0; r < 4; ++r) {
      const int chunk = wave * 4 + r;
      const int row = chunk * 8 + srow;
      const unsigned short* ga = A + (size_t)(m0 + row) * K_DIM + k0 + scol;
      __builtin_amdgcn_global_load_lds(
          (const __attribute__((address_space(1))) void*)ga,
          (__attribute__((address_space(3))) void*)(sA + chunk * 512),
          16, 0, 0);
      const unsigned short* gb = B + (size_t)(n0 + row) * K_DIM + k0 + scol;
      __builtin_amdgcn_global_load_lds(
          (const __attribute__((address_space(1))) void*)gb,
          (__attribute__((address_space(3))) void*)(sB + chunk * 512),
          16, 0, 0);
    }
    __syncthreads();

#pragma unroll
    for (int kk = 0; kk < BK; kk += 32) {
      bf16x8 af[4], bfr[4];
#pragma unroll
      for (int t = 0; t < 4; ++t) {
        const int ra = wm + t * 16 + laneM;
        const int rb = wn + t * 16 + laneM;
        const int c = ((kk >> 3) + q) ^ sw;  // swizzled LDS chunk
        af[t]  = *(const bf16x8*)(sA + ra * BK + c * 8);
        bfr[t] = *(const bf16x8*)(sB + rb * BK + c * 8);
      }
#pragma unroll
      for (int i = 0; i < 4; ++i)
#pragma unroll
        for (int j = 0; j < 4; ++j)
          acc[i][j] = __builtin_amdgcn_mfma_f32_16x16x32_bf16(
              af[i], bfr[j], acc[i][j], 0, 0, 0);
    }
    __syncthreads();
  }

  // C/D layout: col = lane&15, row = (lane>>4)*4 + reg  [m89/m91]
  const int crow = wm + (q << 2);
  const int ccol = wn + laneM;
#pragma unroll
  for (int i = 0; i < 4; ++i)
#pragma unroll
    for (int j = 0; j < 4; ++j) {
      float* cp = C + (size_t)(m0 + crow + i * 16) * N_DIM + (n0 + ccol + j * 16);
#pragma unroll
      for (int r2 = 0; r2 < 4; ++r2)
        cp[(size_t)r2 * N_DIM] = acc[i][j][r2];
    }
}

// Safety-net fallback (only if ws_size < 160 MB): correct fp32, slow.
__global__ void naive_kernel(const float* __restrict__ x,
                             const int* __restrict__ qw,
                             const float* __restrict__ lut,
                             float* __restrict__ out) {
  int o = blockIdx.x * blockDim.x + threadIdx.x;
  int s = blockIdx.y;
  const float* xr = x + (size_t)s * K_DIM;
  const unsigned int* qr = (const unsigned int*)qw + (size_t)o * (K_DIM / 4);
  const float* l = lut + o * 16;
  float acc = 0.f;
  for (int w = 0; w < K_DIM / 4; ++w) {
    unsigned int q = qr[w];
    acc += xr[w * 4 + 0] * l[(q >> 4) & 15u]
         + xr[w * 4 + 1] * l[(q >> 12) & 15u]
         + xr[w * 4 + 2] * l[(q >> 20) & 15u]
         + xr[w * 4 + 3] * l[(q >> 28) & 15u];
  }
  out[(size_t)s * N_DIM + o] = acc;
}

extern "C" void kernel_launch(void* const* d_in, const int* in_sizes, int n_in,
                              void* d_out, int out_size, void* d_ws, size_t ws_size,
                              hipStream_t stream) {
  const float* x   = (const float*)d_in[0];
  const int*   qw  = (const int*)d_in[1];
  const float* lut = (const float*)d_in[2];
  float* out = (float*)d_out;

  const size_t wb_elems = (size_t)N_DIM * K_DIM;   // 128 MB bf16
  const size_t xb_elems = (size_t)M_DIM * K_DIM;   //  32 MB bf16
  const size_t need = (wb_elems + xb_elems) * sizeof(unsigned short);

  if (ws_size >= need) {
    unsigned short* wb = (unsigned short*)d_ws;
    unsigned short* xb = wb + wb_elems;

    hipLaunchKernelGGL(dequant_kernel, dim3(N_DIM), dim3(256), 0, stream,
                       (const int4*)qw, lut, wb);

    const int n_thr = M_DIM * K_DIM / 8;           // 8 elem/thread
    hipLaunchKernelGGL(cvt_x_kernel, dim3(n_thr / 256), dim3(256), 0, stream,
                       (const float4*)x, (unsigned int*)xb);

    dim3 grid(N_DIM / BN, M_DIM / BM);             // 64 x 16 = 1024 blocks
    hipLaunchKernelGGL(gemm_bt, grid, dim3(256), 0, stream, xb, wb, out);
  } else {
    dim3 grid(N_DIM / 256, M_DIM);
    hipLaunchKernelGGL(naive_kernel, grid, dim3(256), 0, stream, x, qw, lut, out);
  }
}

// Round 3
// 498.690 us; speedup vs baseline: 1.2203x; 1.0678x over previous
//
#include <hip/hip_runtime.h>
#include <stdint.h>

// AnyprecisionLinear: out[s,o] = sum_k x[s,k] * lut[o, code(o,k)>>4]
// M=2048, N=8192, K=8192. fp32 in/out, bf16 MFMA compute.
//
// R3 changes vs R2:
//  - dequant: one WAVE per output row; per-lane replicated LUT in LDS with
//    entry-stride 256 B / lane-stride 4 B -> bank = lane%32 regardless of the
//    data-dependent code (truly conflict-free gather; R2's stride-34 scheme
//    collided under data-dependent entries). No cross-lane deps, no barrier.
//  - gemm_bt: 16x16x32 -> 32x32x16 MFMA (m119: 2495 vs 2075 TF; halves MFMA
//    instruction count at same LDS traffic). Same XOR-swizzled LDS + width-16
//    global_load_lds staging (R2 measured 0 bank conflicts).

#define M_DIM 2048
#define N_DIM 8192
#define K_DIM 8192
#define BM 128
#define BN 128
#define BK 64

typedef __bf16 bf16x8 __attribute__((ext_vector_type(8)));
typedef float f32x16 __attribute__((ext_vector_type(16)));

__device__ __forceinline__ unsigned int f2bf(float f) {
  // round-to-nearest-even fp32 -> bf16
  unsigned int u = __float_as_uint(f);
  return (u + 0x7FFFu + ((u >> 16) & 1u)) >> 16;
}

// ---------------- dequant: qweight (int32-packed 8-bit codes) -> bf16 W ----
// One wave per output row; block = 4 waves = 4 rows; 2048 blocks.
// LDS: per wave a 4 KB table, entry e / lane l at dword index e*64 + l.
//   byte addr = e*256 + l*4 -> bank = l % 32 (data-independent, conflict-free;
//   lanes l and l+32 are the free 2-way alias). Lane l only ever reads the
//   column it wrote -> no synchronization needed at all.
__global__ __launch_bounds__(256) void dequant_kernel(
    const int4* __restrict__ qw4,
    const float* __restrict__ lut,
    unsigned short* __restrict__ wb) {
  __shared__ unsigned int slut[4 * 16 * 64];  // 16 KB
  const int wave = threadIdx.x >> 6;
  const int lane = threadIdx.x & 63;
  const int row = (blockIdx.x << 2) + wave;

  unsigned int* tbl = slut + wave * (16 * 64) + lane;  // this lane's column
  const float* lr = lut + row * 16;
#pragma unroll
  for (int e = 0; e < 16; ++e) tbl[e * 64] = f2bf(lr[e]);

  const int4* src = qw4 + (size_t)row * 512 + lane;          // 512 int4/row
  unsigned short* dst = wb + (size_t)row * K_DIM + lane * 16;

#pragma unroll
  for (int it = 0; it < 8; ++it) {
    int4 q = src[it * 64];
    unsigned int w[4] = {(unsigned int)q.x, (unsigned int)q.y,
                         (unsigned int)q.z, (unsigned int)q.w};
    unsigned int v[16];
#pragma unroll
    for (int j = 0; j < 4; ++j) {
#pragma unroll
      for (int k = 0; k < 4; ++k)
        v[j * 4 + k] = tbl[((w[j] >> (8 * k + 4)) & 15u) * 64];
    }
    uint4 o0, o1;
    o0.x = v[0] | (v[1] << 16);   o0.y = v[2]  | (v[3] << 16);
    o0.z = v[4] | (v[5] << 16);   o0.w = v[6]  | (v[7] << 16);
    o1.x = v[8] | (v[9] << 16);   o1.y = v[10] | (v[11] << 16);
    o1.z = v[12] | (v[13] << 16); o1.w = v[14] | (v[15] << 16);
    uint4* dp = (uint4*)(dst + it * 1024);
    dp[0] = o0;
    dp[1] = o1;
  }
}

// ---------------- x fp32 -> bf16, 8 elements/thread, 16 B stores -----------
__global__ __launch_bounds__(256) void cvt_x_kernel(
    const float4* __restrict__ x4, unsigned int* __restrict__ xb) {
  const int idx = blockIdx.x * 256 + threadIdx.x;
  float4 a = x4[2 * idx];
  float4 b = x4[2 * idx + 1];
  uint4 o;
  o.x = f2bf(a.x) | (f2bf(a.y) << 16);
  o.y = f2bf(a.z) | (f2bf(a.w) << 16);
  o.z = f2bf(b.x) | (f2bf(b.y) << 16);
  o.w = f2bf(b.z) | (f2bf(b.w) << 16);
  ((uint4*)xb)[idx] = o;
}

// ---------------- GEMM: C = A * B^T, 32x32x16 bf16 MFMA, swizzled LDS ------
// A: M x K bf16 row-major, B: N x K bf16 row-major, C: M x N fp32.
// Block 256 thr (4 waves), tile 128x128, BK=64, 32 KB LDS single-buffered.
// Wave tile 64x64 = 2x2 of 32x32. LDS chunk c of row r holds GLOBAL k-chunk
// c ^ (r&7) (same swizzle as R2; measured 0 bank conflicts).
// A/B operand: row/col = lane&31, k = (lane>>5)*8 + j.
// C/D: col = lane&31, row = (reg&3) + 8*(reg>>2) + 4*(lane>>5)  [m74/m101].
__global__ __launch_bounds__(256) void gemm_bt(
    const unsigned short* __restrict__ A,
    const unsigned short* __restrict__ B,
    float* __restrict__ C) {
  __shared__ __align__(16) unsigned short sA[BM * BK];  // 16 KB
  __shared__ __align__(16) unsigned short sB[BN * BK];  // 16 KB

  const int tid = threadIdx.x;
  const int wave = tid >> 6;
  const int lane = tid & 63;
  const int m0 = blockIdx.y * BM;
  const int n0 = blockIdx.x * BN;
  const int wm = (wave & 1) * 64;
  const int wn = (wave >> 1) * 64;

  // staging source coords (swizzled column), identical to R2
  const int srow = lane >> 3;
  const int scol = ((lane & 7) ^ (lane >> 3)) * 8;

  const int laneN = lane & 31;   // operand m/n index
  const int half = lane >> 5;    // k-half (0: k 0-7, 1: k 8-15)
  const int sw = laneN & 7;      // reader XOR key (== row&7)

  f32x16 acc[2][2];
#pragma unroll
  for (int i = 0; i < 2; ++i)
#pragma unroll
    for (int j = 0; j < 2; ++j)
#pragma unroll
      for (int r = 0; r < 16; ++r) acc[i][j][r] = 0.0f;

  for (int k0 = 0; k0 < K_DIM; k0 += BK) {
#pragma unroll
    for (int r = 0; r < 4; ++r) {
      const int chunk = wave * 4 + r;
      const int row = chunk * 8 + srow;
      const unsigned short* ga = A + (size_t)(m0 + row) * K_DIM + k0 + scol;
      __builtin_amdgcn_global_load_lds(
          (const __attribute__((address_space(1))) void*)ga,
          (__attribute__((address_space(3))) void*)(sA + chunk * 512),
          16, 0, 0);
      const unsigned short* gb = B + (size_t)(n0 + row) * K_DIM + k0 + scol;
      __builtin_amdgcn_global_load_lds(
          (const __attribute__((address_space(1))) void*)gb,
          (__attribute__((address_space(3))) void*)(sB + chunk * 512),
          16, 0, 0);
    }
    __syncthreads();

#pragma unroll
    for (int kk = 0; kk < BK; kk += 16) {
      const int c = ((kk >> 3) + half) ^ sw;  // swizzled LDS chunk
      bf16x8 af[2], bfr[2];
#pragma unroll
      for (int t = 0; t < 2; ++t) {
        af[t]  = *(const bf16x8*)(sA + (wm + t * 32 + laneN) * BK + c * 8);
        bfr[t] = *(const bf16x8*)(sB + (wn + t * 32 + laneN) * BK + c * 8);
      }
#pragma unroll
      for (int i = 0; i < 2; ++i)
#pragma unroll
        for (int j = 0; j < 2; ++j)
          acc[i][j] = __builtin_amdgcn_mfma_f32_32x32x16_bf16(
              af[i], bfr[j], acc[i][j], 0, 0, 0);
    }
    __syncthreads();
  }

  // epilogue: C/D layout col=lane&31, row=(reg&3)+8*(reg>>2)+4*half
#pragma unroll
  for (int i = 0; i < 2; ++i)
#pragma unroll
    for (int j = 0; j < 2; ++j) {
      const int rbase = m0 + wm + i * 32 + 4 * half;
      const int col = n0 + wn + j * 32 + laneN;
#pragma unroll
      for (int r = 0; r < 16; ++r) {
        const int rrow = rbase + (r & 3) + 8 * (r >> 2);
        C[(size_t)rrow * N_DIM + col] = acc[i][j][r];
      }
    }
}

// Safety-net fallback (only if ws_size < 160 MB): correct fp32, slow.
__global__ void naive_kernel(const float* __restrict__ x,
                             const int* __restrict__ qw,
                             const float* __restrict__ lut,
                             float* __restrict__ out) {
  int o = blockIdx.x * blockDim.x + threadIdx.x;
  int s = blockIdx.y;
  const float* xr = x + (size_t)s * K_DIM;
  const unsigned int* qr = (const unsigned int*)qw + (size_t)o * (K_DIM / 4);
  const float* l = lut + o * 16;
  float acc = 0.f;
  for (int w = 0; w < K_DIM / 4; ++w) {
    unsigned int q = qr[w];
    acc += xr[w * 4 + 0] * l[(q >> 4) & 15u]
         + xr[w * 4 + 1] * l[(q >> 12) & 15u]
         + xr[w * 4 + 2] * l[(q >> 20) & 15u]
         + xr[w * 4 + 3] * l[(q >> 28) & 15u];
  }
  out[(size_t)s * N_DIM + o] = acc;
}

extern "C" void kernel_launch(void* const* d_in, const int* in_sizes, int n_in,
                              void* d_out, int out_size, void* d_ws, size_t ws_size,
                              hipStream_t stream) {
  const float* x   = (const float*)d_in[0];
  const int*   qw  = (const int*)d_in[1];
  const float* lut = (const float*)d_in[2];
  float* out = (float*)d_out;

  const size_t wb_elems = (size_t)N_DIM * K_DIM;   // 128 MB bf16
  const size_t xb_elems = (size_t)M_DIM * K_DIM;   //  32 MB bf16
  const size_t need = (wb_elems + xb_elems) * sizeof(unsigned short);

  if (ws_size >= need) {
    unsigned short* wb = (unsigned short*)d_ws;
    unsigned short* xb = wb + wb_elems;

    hipLaunchKernelGGL(dequant_kernel, dim3(N_DIM / 4), dim3(256), 0, stream,
                       (const int4*)qw, lut, wb);

    const int n_thr = M_DIM * K_DIM / 8;           // 8 elem/thread
    hipLaunchKernelGGL(cvt_x_kernel, dim3(n_thr / 256), dim3(256), 0, stream,
                       (const float4*)x, (unsigned int*)xb);

    dim3 grid(N_DIM / BN, M_DIM / BM);             // 64 x 16 = 1024 blocks
    hipLaunchKernelGGL(gemm_bt, grid, dim3(256), 0, stream, xb, wb, out);
  } else {
    dim3 grid(N_DIM / 256, M_DIM);
    hipLaunchKernelGGL(naive_kernel, grid, dim3(256), 0, stream, x, qw, lut, out);
  }
}